// Round 1
// baseline (390.688 us; speedup 1.0000x reference)
//
#include <hip/hip_runtime.h>
#include <hip/hip_bf16.h>

#define S_LEN 2048
#define DH 64
#define QBLK 64
#define KVBLK 64
#define NQT (S_LEN / QBLK)   // 32 q-tiles per head

// LDS row pitches in bf16 elements (144 bytes -> 16B aligned, ~2-way banks max)
#define KP 72
#define VP 72
#define PP 72

typedef short bf16x8 __attribute__((ext_vector_type(8)));
typedef short bf16x4 __attribute__((ext_vector_type(4)));
typedef float f32x4  __attribute__((ext_vector_type(4)));

__device__ __forceinline__ short f2bf(float f) {
    union { float f; unsigned u; } x; x.f = f;
    unsigned r = x.u + 0x7fffu + ((x.u >> 16) & 1u);   // round-to-nearest-even
    return (short)(r >> 16);
}

__global__ __launch_bounds__(256)
void attn_fwd(const float* __restrict__ qg, const float* __restrict__ kg,
              const float* __restrict__ vg, const int* __restrict__ maskg,
              float* __restrict__ outg)
{
    __shared__ short Kt[KVBLK][KP];     // K tile, [kv][d] bf16
    __shared__ short Vt[DH][VP];        // V tile transposed, [d][kv] bf16
    __shared__ short Pl[4][16][PP];     // per-wave P tile, [q][kv] bf16

    const int tid  = threadIdx.x;
    const int lane = tid & 63;
    const int wid  = tid >> 6;
    const int g    = lane >> 4;     // 16-lane group 0..3
    const int lc   = lane & 15;

    const int bh = blockIdx.x / NQT;
    const int qt = blockIdx.x % NQT;
    const int q0 = qt * QBLK + wid * 16;    // this wave's first q row

    const size_t base = (size_t)bh * S_LEN * DH;
    const float* qp = qg + base;
    const float* kp = kg + base;
    const float* vp = vg + base;

    // ---- Q fragments (pre-scaled by 1/sqrt(64)=0.125, exact in bf16) ----
    // lane holds Q[q0+lc][g*8 + i + ks*32], i=0..7
    bf16x8 qf[2];
    #pragma unroll
    for (int ks = 0; ks < 2; ++ks) {
        const float* src = qp + (size_t)(q0 + lc) * DH + g * 8 + ks * 32;
        f32x4 a = *(const f32x4*)src;
        f32x4 b = *(const f32x4*)(src + 4);
        bf16x8 t;
        #pragma unroll
        for (int i = 0; i < 4; ++i) {
            t[i]     = f2bf(a[i] * 0.125f);
            t[i + 4] = f2bf(b[i] * 0.125f);
        }
        qf[ks] = t;
    }

    // ---- online softmax state; o C-layout: row=g*4+r, col(d)=nt*16+lc ----
    float m[4], l[4];
    f32x4 o[4];
    #pragma unroll
    for (int r = 0; r < 4; ++r) {
        m[r] = -1e30f; l[r] = 0.f;
        #pragma unroll
        for (int j = 0; j < 4; ++j) o[r][j] = 0.f;
    }

    for (int kv0 = 0; kv0 < S_LEN; kv0 += KVBLK) {
        __syncthreads();   // previous tile's LDS reads done

        // ---- stage K (row-major) and V (transposed) into LDS, fp32->bf16 ----
        #pragma unroll
        for (int it = 0; it < 4; ++it) {
            int idx = tid + it * 256;          // 0..1023 float4s
            int kvr = idx >> 4;                // 0..63
            int d4  = (idx & 15) << 2;         // 0,4,..,60
            f32x4 kf = *(const f32x4*)(kp + (size_t)(kv0 + kvr) * DH + d4);
            bf16x4 ks4;
            #pragma unroll
            for (int j = 0; j < 4; ++j) ks4[j] = f2bf(kf[j]);
            *(bf16x4*)&Kt[kvr][d4] = ks4;
            f32x4 vf = *(const f32x4*)(vp + (size_t)(kv0 + kvr) * DH + d4);
            #pragma unroll
            for (int j = 0; j < 4; ++j) Vt[d4 + j][kvr] = f2bf(vf[j]);
        }
        __syncthreads();

        // ---- QK^T: S[16q x 64kv] as 4 n-tiles, K-contraction over d=64 ----
        f32x4 sacc[4];
        #pragma unroll
        for (int nt = 0; nt < 4; ++nt) {
            #pragma unroll
            for (int j = 0; j < 4; ++j) sacc[nt][j] = 0.f;
            #pragma unroll
            for (int ks = 0; ks < 2; ++ks) {
                bf16x8 bf = *(const bf16x8*)&Kt[nt * 16 + lc][g * 8 + ks * 32];
                sacc[nt] = __builtin_amdgcn_mfma_f32_16x16x32_bf16(qf[ks], bf, sacc[nt], 0, 0, 0);
            }
        }

        // ---- mask add (fp32), online softmax over this 64-col tile ----
        float sv[4][4];
        const int mrow0 = q0 + g * 4;
        #pragma unroll
        for (int nt = 0; nt < 4; ++nt) {
            #pragma unroll
            for (int r = 0; r < 4; ++r) {
                int mv = maskg[(size_t)(mrow0 + r) * S_LEN + kv0 + nt * 16 + lc];
                sv[nt][r] = sacc[nt][r] - 10000.0f * (float)mv;
            }
        }
        float al[4];
        #pragma unroll
        for (int r = 0; r < 4; ++r) {
            float v0 = fmaxf(fmaxf(sv[0][r], sv[1][r]), fmaxf(sv[2][r], sv[3][r]));
            v0 = fmaxf(v0, __shfl_xor(v0, 1));
            v0 = fmaxf(v0, __shfl_xor(v0, 2));
            v0 = fmaxf(v0, __shfl_xor(v0, 4));
            v0 = fmaxf(v0, __shfl_xor(v0, 8));
            float mn = fmaxf(m[r], v0);
            al[r] = __expf(m[r] - mn);
            m[r] = mn;
        }
        float p[4][4];
        float rsum[4] = {0.f, 0.f, 0.f, 0.f};
        #pragma unroll
        for (int nt = 0; nt < 4; ++nt)
            #pragma unroll
            for (int r = 0; r < 4; ++r) {
                p[nt][r] = __expf(sv[nt][r] - m[r]);
                rsum[r] += p[nt][r];
            }
        #pragma unroll
        for (int r = 0; r < 4; ++r) {
            float s = rsum[r];
            s += __shfl_xor(s, 1);
            s += __shfl_xor(s, 2);
            s += __shfl_xor(s, 4);
            s += __shfl_xor(s, 8);
            l[r] = l[r] * al[r] + s;
            #pragma unroll
            for (int nt = 0; nt < 4; ++nt) o[nt][r] *= al[r];
        }

        // ---- P -> per-wave LDS (transpose from C-layout to A-operand layout) ----
        #pragma unroll
        for (int nt = 0; nt < 4; ++nt)
            #pragma unroll
            for (int r = 0; r < 4; ++r)
                Pl[wid][g * 4 + r][nt * 16 + lc] = f2bf(p[nt][r]);

        // ---- PV: O[16q x 64d] += P[16q x 64kv] * V[64kv x 64d] ----
        #pragma unroll
        for (int ks = 0; ks < 2; ++ks) {
            bf16x8 pa = *(const bf16x8*)&Pl[wid][lc][g * 8 + ks * 32];
            #pragma unroll
            for (int nt = 0; nt < 4; ++nt) {
                bf16x8 vb = *(const bf16x8*)&Vt[nt * 16 + lc][g * 8 + ks * 32];
                o[nt] = __builtin_amdgcn_mfma_f32_16x16x32_bf16(pa, vb, o[nt], 0, 0, 0);
            }
        }
    }

    // ---- epilogue: normalize by l, write fp32 ----
    float inv[4];
    #pragma unroll
    for (int r = 0; r < 4; ++r) inv[r] = 1.0f / l[r];
    float* op = outg + base;
    #pragma unroll
    for (int nt = 0; nt < 4; ++nt)
        #pragma unroll
        for (int r = 0; r < 4; ++r)
            op[(size_t)(q0 + g * 4 + r) * DH + nt * 16 + lc] = o[nt][r] * inv[r];
}

extern "C" void kernel_launch(void* const* d_in, const int* in_sizes, int n_in,
                              void* d_out, int out_size, void* d_ws, size_t ws_size,
                              hipStream_t stream) {
    const float* q = (const float*)d_in[0];
    const float* k = (const float*)d_in[1];
    const float* v = (const float*)d_in[2];
    const int* mask = (const int*)d_in[3];
    float* out = (float*)d_out;
    const int BH = 2 * 16;
    dim3 grid(BH * NQT);   // 1024 blocks
    dim3 block(256);
    attn_fwd<<<grid, block, 0, stream>>>(q, k, v, mask, out);
}

// Round 2
// 140.471 us; speedup vs baseline: 2.7813x; 2.7813x over previous
//
#include <hip/hip_runtime.h>
#include <hip/hip_bf16.h>
#include <stdint.h>

#define S_LEN 2048
#define DH 64
#define NT 32          // kv tiles of 64
#define NQT 32         // q tiles of 64
#define BHN 32         // B*H

typedef short bf16x8 __attribute__((ext_vector_type(8)));
typedef short bf16x4 __attribute__((ext_vector_type(4)));
typedef float f32x4  __attribute__((ext_vector_type(4)));

__device__ __forceinline__ short f2bf(float f) {
    union { float f; unsigned u; } x; x.f = f;
    unsigned r = x.u + 0x7fffu + ((x.u >> 16) & 1u);   // RNE
    return (short)(r >> 16);
}

// ws layout (bytes):
//   [0, 512K)        : mask bits  uint64 mb[2048][32]   (bit j of word w = mask[row][w*64+j])
//   [512K, +8M)      : K  bf16 swizzled [bh][tile][kv][64]  (16B slot s stored at s^(kv&7))
//   [512K+8M, +8M)   : V^T bf16 swizzled [bh][tile][d][64]  (16B slot s stored at s^(d&7))
#define MB_OFF 0
#define KP_OFF (512u * 1024u)
#define VP_OFF (512u * 1024u + 8u * 1024u * 1024u)

// ---------------- prep kernels ----------------

__global__ __launch_bounds__(256) void pack_mask(const int* __restrict__ mask,
                                                 unsigned long long* __restrict__ mb) {
    int t = blockIdx.x * 256 + threadIdx.x;      // 65536 = 2048 rows * 32 words
    int row = t >> 5, word = t & 31;
    const int4* p = (const int4*)(mask + (size_t)row * S_LEN + word * 64);
    unsigned long long w = 0ull;
    #pragma unroll
    for (int j = 0; j < 16; ++j) {
        int4 v = p[j];
        unsigned b = (unsigned)((v.x != 0) | ((v.y != 0) << 1) | ((v.z != 0) << 2) | ((v.w != 0) << 3));
        w |= (unsigned long long)b << (j * 4);
    }
    mb[t] = w;
}

__global__ __launch_bounds__(256) void prep_k(const float* __restrict__ kg,
                                              short* __restrict__ kp) {
    int t = blockIdx.x * 256 + threadIdx.x;      // 524288 = 32bh * 2048kv * 8slots
    int s = t & 7; int kvg = (t >> 3) & 2047; int bh = t >> 14;
    const float* src = kg + (((size_t)bh * S_LEN + kvg) << 6) + s * 8;
    f32x4 a = *(const f32x4*)src;
    f32x4 b = *(const f32x4*)(src + 4);
    bf16x8 o;
    #pragma unroll
    for (int j = 0; j < 4; ++j) { o[j] = f2bf(a[j]); o[j + 4] = f2bf(b[j]); }
    int tile = kvg >> 6, kv = kvg & 63;
    short* dst = kp + ((((size_t)bh * NT + tile) * 64 + kv) << 6) + ((s ^ (kv & 7)) << 3);
    *(bf16x8*)dst = o;
}

__global__ __launch_bounds__(256) void prep_v(const float* __restrict__ vg,
                                              short* __restrict__ vp) {
    __shared__ __align__(16) short T[64][72];   // [d][kv], padded
    int bh = blockIdx.x >> 5, tile = blockIdx.x & 31;
    const float* src = vg + ((size_t)bh * S_LEN + tile * 64) * DH;
    int tid = threadIdx.x;
    #pragma unroll
    for (int it = 0; it < 4; ++it) {
        int idx = tid + it * 256;              // 0..1023
        int kv = idx >> 4, d4 = (idx & 15) << 2;
        f32x4 a = *(const f32x4*)(src + kv * 64 + d4);
        #pragma unroll
        for (int j = 0; j < 4; ++j) T[d4 + j][kv] = f2bf(a[j]);
    }
    __syncthreads();
    short* dst = vp + (((size_t)bh * NT + tile) << 12);
    #pragma unroll
    for (int it = 0; it < 2; ++it) {
        int idx = tid + it * 256;              // 0..511 = 64 d * 8 slots
        int d = idx >> 3, s = idx & 7;
        bf16x8 o = *(const bf16x8*)&T[d][s * 8];   // byte 144*d+16*s, 16B aligned
        *(bf16x8*)(dst + (d << 6) + ((s ^ (d & 7)) << 3)) = o;
    }
}

// ---------------- main kernel ----------------

__device__ __forceinline__ void gll16(const void* g, void* l) {
    __builtin_amdgcn_global_load_lds(
        (const __attribute__((address_space(1))) unsigned int*)g,
        (__attribute__((address_space(3))) unsigned int*)l, 16, 0, 0);
}

__global__ __launch_bounds__(256)
void attn_fwd(const float* __restrict__ qg, const unsigned long long* __restrict__ mb,
              const short* __restrict__ kp, const short* __restrict__ vp,
              float* __restrict__ outg)
{
    __shared__ __align__(16) short Kd[2][4096];   // [kv][64] bf16, slot-swizzled
    __shared__ __align__(16) short Vd[2][4096];   // [d][64kv] bf16, slot-swizzled
    __shared__ __align__(16) short Pl[4][1024];   // per-wave [16q][64kv], slot-swizzled

    const int tid  = threadIdx.x;
    const int lane = tid & 63;
    const int wid  = tid >> 6;
    const int g    = lane >> 4;
    const int lc   = lane & 15;
    const int xorp = (lc & 7) << 4;   // 16B-slot XOR pattern for rows this lane reads

    // XCD-bijective swizzle: 1024 wg, 8 XCDs -> each XCD gets 4 whole heads
    int bid = blockIdx.x;
    int wg  = (bid & 7) * 128 + (bid >> 3);
    const int bh = wg >> 5, qt = wg & 31;
    const int q0 = qt * 64 + wid * 16;

    const size_t base = (size_t)bh * S_LEN * DH;

    // Q fragments, pre-scaled by 1/8 (lane holds Q[q0+lc][g*8 + ks*32 + i])
    bf16x8 qf[2];
    #pragma unroll
    for (int ks = 0; ks < 2; ++ks) {
        const float* src = qg + base + (size_t)(q0 + lc) * DH + g * 8 + ks * 32;
        f32x4 a = *(const f32x4*)src;
        f32x4 b = *(const f32x4*)(src + 4);
        bf16x8 tq;
        #pragma unroll
        for (int i = 0; i < 4; ++i) { tq[i] = f2bf(a[i] * 0.125f); tq[i + 4] = f2bf(b[i] * 0.125f); }
        qf[ks] = tq;
    }

    const short* ktile = kp + (size_t)bh * NT * 4096;
    const short* vtile = vp + (size_t)bh * NT * 4096;
    const unsigned long long* mrow = mb + (size_t)(q0 + g * 4) * 32;

    float m[4], l[4];
    f32x4 o[4];
    #pragma unroll
    for (int r = 0; r < 4; ++r) {
        m[r] = -1e30f; l[r] = 0.f;
        #pragma unroll
        for (int j = 0; j < 4; ++j) o[r][j] = 0.f;
    }

    unsigned long long mcur[4], mnxt[4];

    // prologue: stage tile 0, mask words 0
    #pragma unroll
    for (int c = 0; c < 2; ++c) {
        int ck = wid * 2 + c;
        gll16(ktile + ck * 512 + lane * 8, &Kd[0][ck * 512]);
        gll16(vtile + ck * 512 + lane * 8, &Vd[0][ck * 512]);
    }
    #pragma unroll
    for (int r = 0; r < 4; ++r) mcur[r] = mrow[r * 32];
    asm volatile("s_waitcnt vmcnt(0)" ::: "memory");
    __syncthreads();

    for (int t = 0; t < NT; ++t) {
        const int b = t & 1;
        // prefetch tile t+1 (direct-to-LDS) + next mask words; lands during compute
        if (t + 1 < NT) {
            const short* kt1 = ktile + (t + 1) * 4096;
            const short* vt1 = vtile + (t + 1) * 4096;
            #pragma unroll
            for (int c = 0; c < 2; ++c) {
                int ck = wid * 2 + c;
                gll16(kt1 + ck * 512 + lane * 8, &Kd[b ^ 1][ck * 512]);
                gll16(vt1 + ck * 512 + lane * 8, &Vd[b ^ 1][ck * 512]);
            }
            #pragma unroll
            for (int r = 0; r < 4; ++r) mnxt[r] = mrow[r * 32 + t + 1];
        }

        // ---- QK^T ----
        f32x4 sacc[4];
        #pragma unroll
        for (int nt = 0; nt < 4; ++nt) {
            #pragma unroll
            for (int j = 0; j < 4; ++j) sacc[nt][j] = 0.f;
            #pragma unroll
            for (int ks = 0; ks < 2; ++ks) {
                const char* ka = (const char*)&Kd[b][0] + (nt * 16 + lc) * 128 + (((g << 4) | (ks << 6)) ^ xorp);
                bf16x8 kf = *(const bf16x8*)ka;
                sacc[nt] = __builtin_amdgcn_mfma_f32_16x16x32_bf16(qf[ks], kf, sacc[nt], 0, 0, 0);
            }
        }

        // ---- mask (bits) + online softmax ----
        float sv[4][4];
        #pragma unroll
        for (int nt = 0; nt < 4; ++nt) {
            #pragma unroll
            for (int r = 0; r < 4; ++r) {
                unsigned t16 = (unsigned)(mcur[r] >> (nt * 16));
                sv[nt][r] = sacc[nt][r] - 10000.0f * (float)((t16 >> lc) & 1u);
            }
        }
        float al[4];
        #pragma unroll
        for (int r = 0; r < 4; ++r) {
            float v0 = fmaxf(fmaxf(sv[0][r], sv[1][r]), fmaxf(sv[2][r], sv[3][r]));
            v0 = fmaxf(v0, __shfl_xor(v0, 1));
            v0 = fmaxf(v0, __shfl_xor(v0, 2));
            v0 = fmaxf(v0, __shfl_xor(v0, 4));
            v0 = fmaxf(v0, __shfl_xor(v0, 8));
            float mn = fmaxf(m[r], v0);
            al[r] = __expf(m[r] - mn);
            m[r] = mn;
        }
        float p[4][4];
        float rsum[4] = {0.f, 0.f, 0.f, 0.f};
        #pragma unroll
        for (int nt = 0; nt < 4; ++nt)
            #pragma unroll
            for (int r = 0; r < 4; ++r) {
                p[nt][r] = __expf(sv[nt][r] - m[r]);
                rsum[r] += p[nt][r];
            }
        #pragma unroll
        for (int r = 0; r < 4; ++r) {
            float s = rsum[r];
            s += __shfl_xor(s, 1);
            s += __shfl_xor(s, 2);
            s += __shfl_xor(s, 4);
            s += __shfl_xor(s, 8);
            l[r] = l[r] * al[r] + s;
            #pragma unroll
            for (int nt = 0; nt < 4; ++nt) o[nt][r] *= al[r];
        }

        // ---- P -> per-wave LDS (row q, swizzled 16B slots) ----
        #pragma unroll
        for (int nt = 0; nt < 4; ++nt)
            #pragma unroll
            for (int r = 0; r < 4; ++r) {
                int qq = g * 4 + r;
                *(short*)((char*)&Pl[wid][0] + (qq << 7) + (((nt << 5) | (lc << 1)) ^ ((qq & 7) << 4))) = f2bf(p[nt][r]);
            }

        // ---- PV ----
        #pragma unroll
        for (int ks = 0; ks < 2; ++ks) {
            const char* pa_ = (const char*)&Pl[wid][0] + (lc << 7) + (((g << 4) | (ks << 6)) ^ xorp);
            bf16x8 pa = *(const bf16x8*)pa_;
            #pragma unroll
            for (int nt = 0; nt < 4; ++nt) {
                const char* va = (const char*)&Vd[b][0] + (nt * 16 + lc) * 128 + (((g << 4) | (ks << 6)) ^ xorp);
                bf16x8 vb = *(const bf16x8*)va;
                o[nt] = __builtin_amdgcn_mfma_f32_16x16x32_bf16(pa, vb, o[nt], 0, 0, 0);
            }
        }

        #pragma unroll
        for (int r = 0; r < 4; ++r) mcur[r] = mnxt[r];
        asm volatile("s_waitcnt vmcnt(0)" ::: "memory");   // tile t+1 landed
        __syncthreads();
    }

    // ---- epilogue ----
    float inv[4];
    #pragma unroll
    for (int r = 0; r < 4; ++r) inv[r] = 1.0f / l[r];
    float* op = outg + base;
    #pragma unroll
    for (int nt = 0; nt < 4; ++nt)
        #pragma unroll
        for (int r = 0; r < 4; ++r)
            op[(size_t)(q0 + g * 4 + r) * DH + nt * 16 + lc] = o[nt][r] * inv[r];
}

extern "C" void kernel_launch(void* const* d_in, const int* in_sizes, int n_in,
                              void* d_out, int out_size, void* d_ws, size_t ws_size,
                              hipStream_t stream) {
    const float* q = (const float*)d_in[0];
    const float* k = (const float*)d_in[1];
    const float* v = (const float*)d_in[2];
    const int* mask = (const int*)d_in[3];
    float* out = (float*)d_out;
    char* ws = (char*)d_ws;
    unsigned long long* mb = (unsigned long long*)(ws + MB_OFF);
    short* kpre = (short*)(ws + KP_OFF);
    short* vpre = (short*)(ws + VP_OFF);

    pack_mask<<<256, 256, 0, stream>>>(mask, mb);
    prep_k<<<2048, 256, 0, stream>>>(k, kpre);
    prep_v<<<1024, 256, 0, stream>>>(v, vpre);
    attn_fwd<<<1024, 256, 0, stream>>>(q, mb, kpre, vpre, out);
}

// Round 3
// 99.183 us; speedup vs baseline: 3.9391x; 1.4163x over previous
//
#include <hip/hip_runtime.h>
#include <hip/hip_bf16.h>
#include <stdint.h>

#define S_LEN 2048
#define DH 64
#define NT 32          // kv tiles of 64
#define NQT 32         // q tiles of 64

typedef short bf16x8 __attribute__((ext_vector_type(8)));
typedef float f32x4  __attribute__((ext_vector_type(4)));
typedef unsigned u32x2 __attribute__((ext_vector_type(2)));

__device__ __forceinline__ unsigned short f2bf_rn(float f) {
    __hip_bfloat16 h = __float2bfloat16(f);           // RNE, compiler pairs into v_cvt_pk_bf16_f32
    return __builtin_bit_cast(unsigned short, h);
}

// ws layout (bytes):
//   [0, 512K)      : mask bits  ushort mbT[32 t][2048 qrow][4 g], bit (mt*4+r) = mask[qrow][t*64+mt*16+g*4+r]
//   [512K, +8M)    : K  bf16 swizzled [bh][tile][kv][64]   (16B slot s stored at s^(kv&7))
//   [512K+8M, +8M) : V^T bf16 swizzled [bh][tile][d][64kv] (16B slot s stored at s^(d&7))
#define MB_OFF 0
#define KP_OFF (512u * 1024u)
#define VP_OFF (512u * 1024u + 8u * 1024u * 1024u)

// ---------------- prep kernels ----------------

__global__ __launch_bounds__(256) void pack_maskT(const int* __restrict__ mask,
                                                  unsigned short* __restrict__ mbT) {
    int idx = blockIdx.x * 256 + threadIdx.x;     // 262144 = 32 t * 2048 rows * 4 g
    int gg = idx & 3, row = (idx >> 2) & 2047, tt = idx >> 13;
    unsigned w = 0;
    #pragma unroll
    for (int mt = 0; mt < 4; ++mt) {
        const int4 v = *(const int4*)(mask + (size_t)row * S_LEN + tt * 64 + mt * 16 + gg * 4);
        unsigned b = (unsigned)((v.x != 0) | ((v.y != 0) << 1) | ((v.z != 0) << 2) | ((v.w != 0) << 3));
        w |= b << (mt * 4);
    }
    mbT[idx] = (unsigned short)w;
}

__global__ __launch_bounds__(256) void prep_k(const float* __restrict__ kg,
                                              short* __restrict__ kp) {
    int t = blockIdx.x * 256 + threadIdx.x;       // 524288 = 32bh * 2048kv * 8slots
    int s = t & 7; int kvg = (t >> 3) & 2047; int bh = t >> 14;
    const float* src = kg + (((size_t)bh * S_LEN + kvg) << 6) + s * 8;
    f32x4 a = *(const f32x4*)src;
    f32x4 b = *(const f32x4*)(src + 4);
    bf16x8 o;
    #pragma unroll
    for (int j = 0; j < 4; ++j) { o[j] = (short)f2bf_rn(a[j]); o[j + 4] = (short)f2bf_rn(b[j]); }
    int tile = kvg >> 6, kv = kvg & 63;
    short* dst = kp + ((((size_t)bh * NT + tile) * 64 + kv) << 6) + ((s ^ (kv & 7)) << 3);
    *(bf16x8*)dst = o;
}

__global__ __launch_bounds__(256) void prep_v(const float* __restrict__ vg,
                                              short* __restrict__ vp) {
    __shared__ __align__(16) short T[64][72];     // [d][kv], padded
    int bh = blockIdx.x >> 5, tile = blockIdx.x & 31;
    const float* src = vg + ((size_t)bh * S_LEN + tile * 64) * DH;
    int tid = threadIdx.x;
    #pragma unroll
    for (int it = 0; it < 4; ++it) {
        int idx = tid + it * 256;
        int kv = idx >> 4, d4 = (idx & 15) << 2;
        f32x4 a = *(const f32x4*)(src + kv * 64 + d4);
        #pragma unroll
        for (int j = 0; j < 4; ++j) T[d4 + j][kv] = (short)f2bf_rn(a[j]);
    }
    __syncthreads();
    short* dst = vp + (((size_t)bh * NT + tile) << 12);
    #pragma unroll
    for (int it = 0; it < 2; ++it) {
        int idx = tid + it * 256;                 // 64 d * 8 slots
        int d = idx >> 3, s = idx & 7;
        bf16x8 o = *(const bf16x8*)&T[d][s * 8];
        *(bf16x8*)(dst + (d << 6) + ((s ^ (d & 7)) << 3)) = o;
    }
}

// ---------------- main kernel ----------------

__device__ __forceinline__ void gll16(const void* g, void* l) {
    __builtin_amdgcn_global_load_lds(
        (const __attribute__((address_space(1))) unsigned int*)g,
        (__attribute__((address_space(3))) unsigned int*)l, 16, 0, 0);
}

__global__ __launch_bounds__(256)
void attn_fwd(const float* __restrict__ qg, const unsigned short* __restrict__ mbT,
              const short* __restrict__ kp, const short* __restrict__ vp,
              float* __restrict__ outg)
{
    __shared__ __align__(16) short Kd[2][4096];   // [kv][64d], slot-swizzled
    __shared__ __align__(16) short Vd[2][4096];   // [d][64kv], slot-swizzled
    __shared__ __align__(16) short Pl[4][1024];   // per-wave P[16q][64kv], slot-swizzled

    const int tid  = threadIdx.x;
    const int lane = tid & 63;
    const int wid  = tid >> 6;
    const int g    = lane >> 4;
    const int lc   = lane & 15;
    const int xorp = (lc & 7) << 4;

    // XCD-bijective swizzle: 1024 wg, 8 XCDs -> each XCD gets 4 whole heads
    int bid = blockIdx.x;
    int wg  = (bid & 7) * 128 + (bid >> 3);
    const int bh = wg >> 5, qt = wg & 31;
    const int q0 = qt * 64 + wid * 16;

    const size_t base = (size_t)bh * S_LEN * DH;

    // Q fragments, pre-scaled by 1/8; lane holds Q[q0+lc][g*8 + ks*32 + i]
    bf16x8 qf[2];
    #pragma unroll
    for (int ks = 0; ks < 2; ++ks) {
        const float* src = qg + base + (size_t)(q0 + lc) * DH + g * 8 + ks * 32;
        f32x4 a = *(const f32x4*)src;
        f32x4 b = *(const f32x4*)(src + 4);
        bf16x8 tq;
        #pragma unroll
        for (int i = 0; i < 4; ++i) {
            tq[i]     = (short)f2bf_rn(a[i] * 0.125f);
            tq[i + 4] = (short)f2bf_rn(b[i] * 0.125f);
        }
        qf[ks] = tq;
    }

    const short* ktile = kp + (size_t)bh * NT * 4096;
    const short* vtile = vp + (size_t)bh * NT * 4096;
    const unsigned short* mptr = mbT + (size_t)(q0 + lc) * 4 + g;   // + t*8192 per tile

    // softmax state per lane: q-row = q0 + lc
    float m = -1e30f, l = 0.f;
    f32x4 o[4];
    #pragma unroll
    for (int nt = 0; nt < 4; ++nt)
        #pragma unroll
        for (int j = 0; j < 4; ++j) o[nt][j] = 0.f;

    unsigned mcur, mnxt;

    // prologue: stage tile 0 + mask word 0
    #pragma unroll
    for (int c = 0; c < 2; ++c) {
        int ck = wid * 2 + c;
        gll16(ktile + ck * 512 + lane * 8, &Kd[0][ck * 512]);
        gll16(vtile + ck * 512 + lane * 8, &Vd[0][ck * 512]);
    }
    mcur = mptr[0];
    asm volatile("s_waitcnt vmcnt(0)" ::: "memory");
    __syncthreads();

    for (int t = 0; t < NT; ++t) {
        const int b = t & 1;
        if (t + 1 < NT) {
            const short* kt1 = ktile + (t + 1) * 4096;
            const short* vt1 = vtile + (t + 1) * 4096;
            #pragma unroll
            for (int c = 0; c < 2; ++c) {
                int ck = wid * 2 + c;
                gll16(kt1 + ck * 512 + lane * 8, &Kd[b ^ 1][ck * 512]);
                gll16(vt1 + ck * 512 + lane * 8, &Vd[b ^ 1][ck * 512]);
            }
            mnxt = mptr[(size_t)(t + 1) * 8192];
        }

        // ---- QK^T swapped: sacc[mt][r] = S[q0+lc][kv0 + mt*16 + g*4 + r] ----
        f32x4 sacc[4];
        __builtin_amdgcn_s_setprio(1);
        #pragma unroll
        for (int mt = 0; mt < 4; ++mt) {
            #pragma unroll
            for (int j = 0; j < 4; ++j) sacc[mt][j] = 0.f;
            #pragma unroll
            for (int ks = 0; ks < 2; ++ks) {
                const char* ka = (const char*)&Kd[b][0] + (mt * 16 + lc) * 128 + (((g << 4) | (ks << 6)) ^ xorp);
                bf16x8 kf = *(const bf16x8*)ka;
                sacc[mt] = __builtin_amdgcn_mfma_f32_16x16x32_bf16(kf, qf[ks], sacc[mt], 0, 0, 0);
            }
        }
        __builtin_amdgcn_s_setprio(0);

        // ---- in-lane max over raw scores (constant shift cancels in softmax) ----
        float x0 = fmaxf(fmaxf(sacc[0][0], sacc[0][1]), fmaxf(sacc[0][2], sacc[0][3]));
        float x1 = fmaxf(fmaxf(sacc[1][0], sacc[1][1]), fmaxf(sacc[1][2], sacc[1][3]));
        float x2 = fmaxf(fmaxf(sacc[2][0], sacc[2][1]), fmaxf(sacc[2][2], sacc[2][3]));
        float x3 = fmaxf(fmaxf(sacc[3][0], sacc[3][1]), fmaxf(sacc[3][2], sacc[3][3]));
        float vmax = fmaxf(fmaxf(x0, x1), fmaxf(x2, x3));
        vmax = fmaxf(vmax, __shfl_xor(vmax, 16));
        vmax = fmaxf(vmax, __shfl_xor(vmax, 32));

        // ---- defer-max: rescale only when the running max grew by > 8 ----
        if (__any(vmax - m > 8.0f)) {
            float mn = fmaxf(m, vmax);
            float al = __expf(m - mn);
            m = mn;
            l *= al;
            float alr[4];
            #pragma unroll
            for (int r = 0; r < 4; ++r) alr[r] = __shfl(al, g * 20 + r);
            #pragma unroll
            for (int nt = 0; nt < 4; ++nt)
                #pragma unroll
                for (int r = 0; r < 4; ++r) o[nt][r] *= alr[r];
        }

        // ---- p = exp(s - m), masked -> 0; pack to bf16 and write P row ----
        const unsigned msk = mcur;
        float rsm[4];
        #pragma unroll
        for (int mt = 0; mt < 4; ++mt) {
            float pr[4];
            #pragma unroll
            for (int r = 0; r < 4; ++r) {
                float pe = __expf(sacc[mt][r] - m);
                pr[r] = (msk & (1u << (mt * 4 + r))) ? 0.0f : pe;
            }
            rsm[mt] = (pr[0] + pr[1]) + (pr[2] + pr[3]);
            u32x2 pw;
            pw[0] = (unsigned)f2bf_rn(pr[0]) | ((unsigned)f2bf_rn(pr[1]) << 16);
            pw[1] = (unsigned)f2bf_rn(pr[2]) | ((unsigned)f2bf_rn(pr[3]) << 16);
            *(u32x2*)((char*)&Pl[wid][0] + (lc << 7) + (((mt << 5) | (g << 3)) ^ xorp)) = pw;
        }
        float rs = (rsm[0] + rsm[1]) + (rsm[2] + rsm[3]);
        rs += __shfl_xor(rs, 16);
        rs += __shfl_xor(rs, 32);
        l += rs;

        // ---- PV: O[16q][64d] += P[16q][64kv] * V[64kv][64d] ----
        __builtin_amdgcn_s_setprio(1);
        #pragma unroll
        for (int ks = 0; ks < 2; ++ks) {
            const char* pa_ = (const char*)&Pl[wid][0] + (lc << 7) + (((g << 4) | (ks << 6)) ^ xorp);
            bf16x8 pa = *(const bf16x8*)pa_;
            #pragma unroll
            for (int nt = 0; nt < 4; ++nt) {
                const char* va = (const char*)&Vd[b][0] + (nt * 16 + lc) * 128 + (((g << 4) | (ks << 6)) ^ xorp);
                bf16x8 vb = *(const bf16x8*)va;
                o[nt] = __builtin_amdgcn_mfma_f32_16x16x32_bf16(pa, vb, o[nt], 0, 0, 0);
            }
        }
        __builtin_amdgcn_s_setprio(0);

        mcur = mnxt;
        asm volatile("s_waitcnt vmcnt(0)" ::: "memory");   // tile t+1 landed
        __syncthreads();
    }

    // ---- epilogue: broadcast 1/l to o-rows, write fp32 ----
    float invl = 1.0f / l;
    float invr[4];
    #pragma unroll
    for (int r = 0; r < 4; ++r) invr[r] = __shfl(invl, g * 20 + r);
    float* op = outg + base;
    #pragma unroll
    for (int nt = 0; nt < 4; ++nt)
        #pragma unroll
        for (int r = 0; r < 4; ++r)
            op[(size_t)(q0 + g * 4 + r) * DH + nt * 16 + lc] = o[nt][r] * invr[r];
}

extern "C" void kernel_launch(void* const* d_in, const int* in_sizes, int n_in,
                              void* d_out, int out_size, void* d_ws, size_t ws_size,
                              hipStream_t stream) {
    const float* q = (const float*)d_in[0];
    const float* k = (const float*)d_in[1];
    const float* v = (const float*)d_in[2];
    const int* mask = (const int*)d_in[3];
    float* out = (float*)d_out;
    char* ws = (char*)d_ws;
    unsigned short* mbT = (unsigned short*)(ws + MB_OFF);
    short* kpre = (short*)(ws + KP_OFF);
    short* vpre = (short*)(ws + VP_OFF);

    pack_maskT<<<1024, 256, 0, stream>>>(mask, mbT);
    prep_k<<<2048, 256, 0, stream>>>(k, kpre);
    prep_v<<<1024, 256, 0, stream>>>(v, vpre);
    attn_fwd<<<1024, 256, 0, stream>>>(q, mbT, kpre, vpre, out);
}